// Round 17
// baseline (35.392 us; speedup 1.0000x reference)
//
#include <hip/hip_runtime.h>
#include <hip/hip_bf16.h>

// R17: dataflow consolidation. Key insight: kB's K-range [2048,2816) (hA@Wb^T,
// alpha@bias^T) does NOT depend on GEMM1 — moved into kFront as independent
// packed GEMM blocks writing their own bf16 partial planes. Consequences:
//   - kB: K 2816->2048 (s@U only), splitK x8 = UNIFORM 4-step chains (-27%),
//     Mt traffic -27%. Total kB traffic 108->~72MB.
//   - X hA/alpha prep segments DEAD (deleted: 1536 blocks, 3.5MB writes).
//   - Mt Wb/bias prep DEAD (deleted: 96 blocks + LDS transpose).
//   - kFront grid 3168->1792: GEMM1(1024) + Mt-U prep(512) + baseW(128,K=256)
//     + baseB(128,K=512). kC sums 10 planes.
// kB sync: __syncthreads (R16's counted-vmcnt was neutral — reverted).
// LEDGER: F~9.6 fixed, kFront~6->5.5, kB~12->8, kC~3->3.5. Target ~27.
// ws: X 11.5MB | Mt 1.44MB | part[10] 10.5MB

typedef __attribute__((ext_vector_type(8))) short bf16x8;
typedef __attribute__((ext_vector_type(4))) float f32x4;
typedef unsigned short ushort_t;

#define LDA_X 2816
#define N_POOL 512
#define D_POOL 4096

__device__ __forceinline__ void gld16(const ushort_t* g, ushort_t* l) {
    __builtin_amdgcn_global_load_lds((__attribute__((address_space(1))) void*)g,
                                     (__attribute__((address_space(3))) void*)l, 16, 0, 0);
}

__device__ __forceinline__ ushort_t bfb(float x) {
    union { __hip_bfloat16 h; ushort_t u; } c; c.h = __float2bfloat16(x); return c.u;
}

__device__ __forceinline__ float bf2f(ushort_t u) {
    union { unsigned int i; float f; } c; c.i = ((unsigned int)u) << 16; return c.f;
}

__device__ __forceinline__ void write4(ushort_t* p, float4 v) {
    ushort4 w = {bfb(v.x), bfb(v.y), bfb(v.z), bfb(v.w)};
    *(ushort4*)p = w;
}

// =============== kFront: GEMM1(0..1023) | Mt-U prep(1024..1535)
//                 | baseW(1536..1663) | baseB(1664..1791) ===============
__global__ __launch_bounds__(256) void kFront(const float* __restrict__ hA,
                                              const float* __restrict__ pool,
                                              const float* __restrict__ alpha,
                                              const float* __restrict__ Wb,
                                              ushort_t* __restrict__ Xu,
                                              ushort_t* __restrict__ Mt,
                                              ushort_t* __restrict__ part) {
    __shared__ __align__(16) ushort_t shmem[16384];   // 32KB pool
    ushort_t* As = shmem;                             // [2][4096]
    ushort_t* Bs = shmem + 8192;
    const int t = threadIdx.x;
    const int bid = blockIdx.x;

    if (bid >= 1024 && bid < 1536) {   // ---- Mt U prep: Mt[c][4n..] = pool[n][4c..]
        int idx = (bid - 1024) * 256 + t, c = idx >> 9, n = idx & 511;
        write4(Mt + (size_t)c * LDA_X + (n << 2), *(const float4*)&pool[(size_t)n * D_POOL + (c << 2)]);
        return;
    }

    // Common GEMM machinery (64x64 tile, 4 waves 2x2 of 32x32, BK=64, reg-staged)
    const int w = t >> 6, l = t & 63, l16 = l & 15, l4 = l >> 4;
    const int wr = w >> 1, wc = w & 1;
    const int row = t >> 2, cs = t & 3;

    f32x4 acc[2][2];
    #pragma unroll
    for (int i = 0; i < 2; ++i)
        #pragma unroll
        for (int j = 0; j < 2; ++j) acc[i][j] = (f32x4){0.f, 0.f, 0.f, 0.f};

    float4 aR[4], bR[4];

    auto writeLDS_AB = [&](int buf) {
        #pragma unroll
        for (int p = 0; p < 4; ++p) {
            int c0 = (cs + p * 4) << 2;
            int off = row * 64 + (((c0 >> 3) ^ (row & 7)) << 3) + ((c0 >> 2) & 1) * 4;
            ushort4 ua = {bfb(aR[p].x), bfb(aR[p].y), bfb(aR[p].z), bfb(aR[p].w)};
            ushort4 ub = {bfb(bR[p].x), bfb(bR[p].y), bfb(bR[p].z), bfb(bR[p].w)};
            *(ushort4*)&As[buf * 4096 + off] = ua;
            *(ushort4*)&Bs[buf * 4096 + off] = ub;
        }
    };
    auto compute = [&](int buf) {
        bf16x8 af[2][2], bv[2][2];
        #pragma unroll
        for (int mi = 0; mi < 2; ++mi) {
            int arow = wr * 32 + mi * 16 + l16;
            #pragma unroll
            for (int ks = 0; ks < 2; ++ks)
                af[mi][ks] = *(const bf16x8*)&As[buf * 4096 + arow * 64 + (((ks * 4 + l4) ^ (arow & 7)) << 3)];
        }
        #pragma unroll
        for (int ni = 0; ni < 2; ++ni) {
            int brow = wc * 32 + ni * 16 + l16;
            #pragma unroll
            for (int ks = 0; ks < 2; ++ks)
                bv[ni][ks] = *(const bf16x8*)&Bs[buf * 4096 + brow * 64 + (((ks * 4 + l4) ^ (brow & 7)) << 3)];
        }
        #pragma unroll
        for (int ks = 0; ks < 2; ++ks)
            #pragma unroll
            for (int mi = 0; mi < 2; ++mi)
                #pragma unroll
                for (int ni = 0; ni < 2; ++ni)
                    acc[mi][ni] = __builtin_amdgcn_mfma_f32_16x16x32_bf16(af[mi][ks], bv[ni][ks], acc[mi][ni], 0, 0, 0);
    };
    auto epilogueLDS = [&]() {
        __syncthreads();
        float* sc = (float*)shmem;
        #pragma unroll
        for (int mi = 0; mi < 2; ++mi)
            #pragma unroll
            for (int ni = 0; ni < 2; ++ni)
                #pragma unroll
                for (int e = 0; e < 4; ++e)
                    sc[(wr * 32 + mi * 16 + l4 * 4 + e) * 64 + wc * 32 + ni * 16 + l16] = acc[mi][ni][e];
        __syncthreads();
    };

    if (bid < 1024) {  // ---------------- GEMM1: s = alpha * (hA @ V^T) ----------------
        const int bm0 = (bid >> 5) * 64, bn0 = (bid & 31) * 64;
        const int kk = bn0 + row;
        const float* bbase = pool + (size_t)(kk >> 2) * D_POOL + 1024 + (kk & 3) * 256;
        const float* abase = hA + (size_t)(bm0 + row) * 256;
        auto loadRegs = [&](int step) {
            const int a0 = step * 64;
            #pragma unroll
            for (int p = 0; p < 4; ++p) {
                int c0 = (cs + p * 4) << 2;
                aR[p] = *(const float4*)(abase + a0 + c0);
                bR[p] = *(const float4*)(bbase + a0 + c0);
            }
        };
        loadRegs(0); writeLDS_AB(0); __syncthreads();
        int cur = 0;
        #pragma unroll
        for (int it = 0; it < 3; ++it) {   // K=256 -> 4 steps
            loadRegs(it + 1);
            compute(cur);
            writeLDS_AB(cur ^ 1);
            __syncthreads();
            cur ^= 1;
        }
        compute(cur);
        epilogueLDS();
        float* sc = (float*)shmem;
        const int r2 = t >> 2, c0 = (t & 3) * 16;
        const float* arow = alpha + (size_t)(bm0 + r2) * N_POOL;
        __align__(16) ushort_t u[16];
        #pragma unroll
        for (int j = 0; j < 16; ++j)
            u[j] = bfb(sc[r2 * 64 + c0 + j] * arow[(bn0 + c0 + j) >> 2]);
        ushort_t* dst = Xu + (size_t)(bm0 + r2) * LDA_X + bn0 + c0;
        *(uint4*)dst = ((uint4*)u)[0];
        *(uint4*)(dst + 8) = ((uint4*)u)[1];
        return;
    }

    if (bid < 1664) {  // ---------------- baseW: hA @ Wb^T (K=256) -> plane 8 ----------------
        const int b2 = bid - 1536;
        const int bm0 = (b2 >> 2) * 64, bc0 = (b2 & 3) * 64;
        const float* abase = hA + (size_t)(bm0 + row) * 256;
        const float* bbase = Wb + (size_t)(bc0 + row) * 256;
        auto loadRegs = [&](int step) {
            const int a0 = step * 64;
            #pragma unroll
            for (int p = 0; p < 4; ++p) {
                int c0 = (cs + p * 4) << 2;
                aR[p] = *(const float4*)(abase + a0 + c0);
                bR[p] = *(const float4*)(bbase + a0 + c0);
            }
        };
        loadRegs(0); writeLDS_AB(0); __syncthreads();
        int cur = 0;
        #pragma unroll
        for (int it = 0; it < 3; ++it) {   // K=256 -> 4 steps
            loadRegs(it + 1);
            compute(cur);
            writeLDS_AB(cur ^ 1);
            __syncthreads();
            cur ^= 1;
        }
        compute(cur);
        epilogueLDS();
        float* sc = (float*)shmem;
        const int r2 = t >> 2, c0 = (t & 3) * 16;
        __align__(16) ushort_t u[16];
        #pragma unroll
        for (int j = 0; j < 16; ++j) u[j] = bfb(sc[r2 * 64 + c0 + j]);
        ushort_t* P = part + (size_t)8 * (2048 * 256) + (size_t)(bm0 + r2) * 256 + bc0 + c0;
        *(uint4*)P = ((uint4*)u)[0];
        *(uint4*)(P + 8) = ((uint4*)u)[1];
        return;
    }

    {  // ---------------- baseB: alpha @ bias^T (K=512) -> plane 9 ----------------
        const int b2 = bid - 1664;
        const int bm0 = (b2 >> 2) * 64, bc0 = (b2 & 3) * 64;
        const float* abase = alpha + (size_t)(bm0 + row) * N_POOL;
        const int cg = t & 63;             // this thread's c within tile (coalesced gather)
        const int jg = t >> 6;             // wave id -> 16-j group
        float bRv[16];
        auto loadRegsB = [&](int step) {   // A: float4 along j; B: 16 coalesced scalars
            const int j0 = step * 64;
            #pragma unroll
            for (int p = 0; p < 4; ++p) {
                int c0 = (cs + p * 4) << 2;
                aR[p] = *(const float4*)(abase + j0 + c0);
            }
            #pragma unroll
            for (int p = 0; p < 16; ++p)
                bRv[p] = pool[(size_t)(j0 + jg * 16 + p) * D_POOL + 2048 + bc0 + cg];
        };
        auto writeLDSB = [&](int buf) {
            #pragma unroll
            for (int p = 0; p < 4; ++p) {  // A (same swizzled layout)
                int c0 = (cs + p * 4) << 2;
                int off = row * 64 + (((c0 >> 3) ^ (row & 7)) << 3) + ((c0 >> 2) & 1) * 4;
                ushort4 ua = {bfb(aR[p].x), bfb(aR[p].y), bfb(aR[p].z), bfb(aR[p].w)};
                *(ushort4*)&As[buf * 4096 + off] = ua;
            }
            #pragma unroll
            for (int p = 0; p < 16; ++p) { // B: scalar bf16 writes, same swizzle
                int jj = jg * 16 + p;
                Bs[buf * 4096 + cg * 64 + (((jj >> 3) ^ (cg & 7)) << 3) + (jj & 7)] = bfb(bRv[p]);
            }
        };
        loadRegsB(0); writeLDSB(0); __syncthreads();
        int cur = 0;
        #pragma unroll
        for (int it = 0; it < 7; ++it) {   // K=512 -> 8 steps
            loadRegsB(it + 1);
            compute(cur);
            writeLDSB(cur ^ 1);
            __syncthreads();
            cur ^= 1;
        }
        compute(cur);
        epilogueLDS();
        float* sc = (float*)shmem;
        const int r2 = t >> 2, c0 = (t & 3) * 16;
        __align__(16) ushort_t u[16];
        #pragma unroll
        for (int j = 0; j < 16; ++j) u[j] = bfb(sc[r2 * 64 + c0 + j]);
        ushort_t* P = part + (size_t)9 * (2048 * 256) + (size_t)(bm0 + r2) * 256 + bc0 + c0;
        *(uint4*)P = ((uint4*)u)[0];
        *(uint4*)(P + 8) = ((uint4*)u)[1];
    }
}

// ======= kB: GEMM2 s@U only, K=2048, 64x64, splitK x8 (4 uniform steps) =======
__global__ __launch_bounds__(256) void kB(const ushort_t* __restrict__ Xu,
                                          const ushort_t* __restrict__ Mt,
                                          ushort_t* __restrict__ part) {
    __shared__ __align__(16) ushort_t As[2][4096];
    __shared__ __align__(16) ushort_t Bs[2][4096];
    const int t = threadIdx.x;
    const int w = t >> 6, l = t & 63, l16 = l & 15, l4 = l >> 4;
    const int wr = w >> 1, wc = w & 1;
    const int bid = blockIdx.x;                // 0..1023; z-locality (R12)
    const int z = bid & 7;
    const int n = (bid >> 3) & 3;
    const int m = bid >> 5;
    const int bm0 = m * 64, bn0 = n * 64;
    const int kc0 = z * 256;
    const int srow = t >> 3;
    const int schunk = (t & 7) ^ (srow & 7);   // source-side swizzle (rule #21)

    f32x4 acc[2][2];
    #pragma unroll
    for (int i = 0; i < 2; ++i)
        #pragma unroll
        for (int j = 0; j < 2; ++j) acc[i][j] = (f32x4){0.f, 0.f, 0.f, 0.f};

    auto stage = [&](int buf, int k0) {
        #pragma unroll
        for (int h = 0; h < 2; ++h) {
            gld16(Xu + (size_t)(bm0 + srow + h * 32) * LDA_X + k0 + schunk * 8,
                  &As[buf][h * 2048 + w * 512]);
            gld16(Mt + (size_t)(bn0 + srow + h * 32) * LDA_X + k0 + schunk * 8,
                  &Bs[buf][h * 2048 + w * 512]);
        }
    };
    auto compute = [&](int buf) {
        bf16x8 af[2][2], bv[2][2];
        #pragma unroll
        for (int mi = 0; mi < 2; ++mi) {
            int arow = wr * 32 + mi * 16 + l16;
            #pragma unroll
            for (int ks = 0; ks < 2; ++ks)
                af[mi][ks] = *(const bf16x8*)&As[buf][arow * 64 + (((ks * 4 + l4) ^ (arow & 7)) << 3)];
        }
        #pragma unroll
        for (int ni = 0; ni < 2; ++ni) {
            int brow = wc * 32 + ni * 16 + l16;
            #pragma unroll
            for (int ks = 0; ks < 2; ++ks)
                bv[ni][ks] = *(const bf16x8*)&Bs[buf][brow * 64 + (((ks * 4 + l4) ^ (brow & 7)) << 3)];
        }
        #pragma unroll
        for (int ks = 0; ks < 2; ++ks)
            #pragma unroll
            for (int mi = 0; mi < 2; ++mi)
                #pragma unroll
                for (int ni = 0; ni < 2; ++ni)
                    acc[mi][ni] = __builtin_amdgcn_mfma_f32_16x16x32_bf16(af[mi][ks], bv[ni][ks], acc[mi][ni], 0, 0, 0);
    };

    stage(0, kc0);
    __syncthreads();
    int cur = 0;
    #pragma unroll
    for (int it = 0; it < 3; ++it) {           // K=256 -> 4 uniform steps
        stage(cur ^ 1, kc0 + (it + 1) * 64);
        compute(cur);
        __syncthreads();
        cur ^= 1;
    }
    compute(cur);

    __syncthreads();
    float* sc = (float*)&As[0][0];
    #pragma unroll
    for (int mi = 0; mi < 2; ++mi)
        #pragma unroll
        for (int ni = 0; ni < 2; ++ni)
            #pragma unroll
            for (int e = 0; e < 4; ++e)
                sc[(wr * 32 + mi * 16 + l4 * 4 + e) * 64 + wc * 32 + ni * 16 + l16] = acc[mi][ni][e];
    __syncthreads();
    const int r2 = t >> 2, c0 = (t & 3) * 16;
    __align__(16) ushort_t u[16];
    #pragma unroll
    for (int j = 0; j < 16; ++j) u[j] = bfb(sc[r2 * 64 + c0 + j]);
    ushort_t* P = part + (size_t)z * (2048 * 256) + (size_t)(bm0 + r2) * 256 + bn0 + c0;
    *(uint4*)P = ((uint4*)u)[0];
    *(uint4*)(P + 8) = ((uint4*)u)[1];
}

// ================= kC: sum 10 bf16 partials + b_base; residual; LN =================
__global__ __launch_bounds__(256) void kC(const ushort_t* __restrict__ part,
                                          const float* __restrict__ hA,
                                          const float* __restrict__ bb,
                                          const float* __restrict__ gamma_p,
                                          const float* __restrict__ lns,
                                          const float* __restrict__ lnb,
                                          float* __restrict__ out) {
    const int wave = threadIdx.x >> 6;
    const int lane = threadIdx.x & 63;
    const int b = blockIdx.x * 4 + wave;
    const float g = gamma_p[0];
    const size_t base = (size_t)b * 256 + lane * 4;

    float p0 = 0.f, p1 = 0.f, p2 = 0.f, p3 = 0.f;
    #pragma unroll
    for (int z = 0; z < 10; ++z) {
        ushort4 q = *(const ushort4*)&part[(size_t)z * 2048 * 256 + base];
        p0 += bf2f(q.x); p1 += bf2f(q.y); p2 += bf2f(q.z); p3 += bf2f(q.w);
    }
    float4 h  = *(const float4*)&hA[base];
    float4 b4 = *(const float4*)&bb[lane * 4];
    float y0 = h.x + g * (p0 + b4.x);
    float y1 = h.y + g * (p1 + b4.y);
    float y2 = h.z + g * (p2 + b4.z);
    float y3 = h.w + g * (p3 + b4.w);

    float sum = y0 + y1 + y2 + y3;
    float ss  = y0*y0 + y1*y1 + y2*y2 + y3*y3;
    #pragma unroll
    for (int off = 1; off < 64; off <<= 1) {
        sum += __shfl_xor(sum, off);
        ss  += __shfl_xor(ss, off);
    }
    float mu  = sum * (1.0f / 256.0f);
    float var = ss * (1.0f / 256.0f) - mu * mu;
    float inv = rsqrtf(var + 1e-5f);

    float4 sc = *(const float4*)&lns[lane * 4];
    float4 bi = *(const float4*)&lnb[lane * 4];
    float4 o;
    o.x = (y0 - mu) * inv * sc.x + bi.x;
    o.y = (y1 - mu) * inv * sc.y + bi.y;
    o.z = (y2 - mu) * inv * sc.z + bi.z;
    o.w = (y3 - mu) * inv * sc.w + bi.w;
    *(float4*)&out[base] = o;
}

extern "C" void kernel_launch(void* const* d_in, const int* in_sizes, int n_in,
                              void* d_out, int out_size, void* d_ws, size_t ws_size,
                              hipStream_t stream) {
    const float* hA    = (const float*)d_in[0];
    const float* pool  = (const float*)d_in[1];
    const float* alpha = (const float*)d_in[2];
    const float* Wb    = (const float*)d_in[3];
    const float* bb    = (const float*)d_in[4];
    const float* gamma = (const float*)d_in[5];
    const float* lns   = (const float*)d_in[6];
    const float* lnb   = (const float*)d_in[7];
    float* out = (float*)d_out;

    ushort_t* Xu   = (ushort_t*)d_ws;                  // [2048][2816] bf16 (s-seg used)
    ushort_t* Mt   = Xu + (size_t)2048 * LDA_X;        // [256][2816]  bf16 (U cols used)
    ushort_t* part = Mt + (size_t)256 * LDA_X;         // [10][2048][256] bf16

    kFront<<<1792, 256, 0, stream>>>(hA, pool, alpha, Wb, Xu, Mt, part);
    kB<<<1024, 256, 0, stream>>>(Xu, Mt, part);
    kC<<<512, 256, 0, stream>>>(part, hA, bb, gamma, lns, lnb, out);
}

// Round 18
// 31.662 us; speedup vs baseline: 1.1178x; 1.1178x over previous
//
#include <hip/hip_runtime.h>
#include <hip/hip_bf16.h>

// R18: FUSION. Block (m,z) computes GEMM1 tile s[64b][256k] (z-slice) into LDS
// (alpha-scaled), then GEMM2 s@U'[z-slice] with U reg-staged DIRECT from pool
// (U'[k][c] = pool[k>>2][4c+(k&3)], float4-contiguous per c). X and Mt are
// DELETED (no 8MB X write, no ~46MB re-read, no prep). 2 launches:
//   kFused (grid 512 = 256 fused + 128 baseW + 128 baseB; 72KB LDS, 2/CU,
//           all resident) -> planes 0..9
//   kC     (10-plane sum + bias/residual/LN; R17-verified body)
// LDS swizzles (matched write/read): 64x32 & 256x32 tiles: ch^=(row>>1)&3;
// s 64x256: ch^=(row&7). ws: part[10] 10.5MB only.
// LEDGER: F~9.6 fixed; replaces kFront-GEMM1+prep(~5)+kB(~12) with ~5-7us.

typedef __attribute__((ext_vector_type(8))) short bf16x8;
typedef __attribute__((ext_vector_type(4))) float f32x4;
typedef unsigned short ushort_t;

#define N_POOL 512
#define D_POOL 4096

__device__ __forceinline__ ushort_t bfb(float x) {
    union { __hip_bfloat16 h; ushort_t u; } c; c.h = __float2bfloat16(x); return c.u;
}

__device__ __forceinline__ float bf2f(ushort_t u) {
    union { unsigned int i; float f; } c; c.i = ((unsigned int)u) << 16; return c.f;
}

// ===================== kFused =====================
__global__ __launch_bounds__(256) void kFused(const float* __restrict__ hA,
                                              const float* __restrict__ pool,
                                              const float* __restrict__ alpha,
                                              const float* __restrict__ Wb,
                                              ushort_t* __restrict__ part) {
    __shared__ __align__(16) ushort_t shm[36864];   // 72KB
    const int t = threadIdx.x;
    const int bid = blockIdx.x;
    const int w = t >> 6, l = t & 63, l16 = l & 15, l4 = l >> 4;

    if (bid < 256) {
        // ---------------- fused GEMM1 -> s-LDS -> GEMM2 ----------------
        ushort_t* As = shm;              // [2][2048] : 64x32 tile
        ushort_t* Bs = shm + 4096;       // [2][8192] : 256x32 tile
        ushort_t* S_ = shm + 20480;      // [64][256] s-tile
        const int m = bid >> 3, z = bid & 7;
        const int b0 = m * 64;

        f32x4 acc[4][4];
        #pragma unroll
        for (int i = 0; i < 4; ++i)
            #pragma unroll
            for (int j = 0; j < 4; ++j) acc[i][j] = (f32x4){0.f, 0.f, 0.f, 0.f};

        float4 regA[2], regB[8];
        const int rA = t >> 2, cA = t & 3;          // A staging: row, chunk

        // ---- generic compute on As/Bs 32-K tiles (wave w owns out-cols w*64..)
        auto compute = [&](int buf) {
            bf16x8 af[4], bv[4];
            #pragma unroll
            for (int mi = 0; mi < 4; ++mi) {
                int ar = mi * 16 + l16;
                af[mi] = *(const bf16x8*)&As[buf * 2048 + ar * 32 + ((l4 ^ ((ar >> 1) & 3)) << 3)];
            }
            #pragma unroll
            for (int ni = 0; ni < 4; ++ni) {
                int br = w * 64 + ni * 16 + l16;
                bv[ni] = *(const bf16x8*)&Bs[buf * 8192 + br * 32 + ((l4 ^ ((br >> 1) & 3)) << 3)];
            }
            #pragma unroll
            for (int mi = 0; mi < 4; ++mi)
                #pragma unroll
                for (int ni = 0; ni < 4; ++ni)
                    acc[mi][ni] = __builtin_amdgcn_mfma_f32_16x16x32_bf16(af[mi], bv[ni], acc[mi][ni], 0, 0, 0);
        };

        // ================= phase 1: GEMM1 (K=256 over a, 8 steps) =================
        const float* aBase = hA + (size_t)(b0 + rA) * 256;
        auto loadA1 = [&](int st) {
            regA[0] = *(const float4*)(aBase + st * 32 + cA * 8);
            regA[1] = *(const float4*)(aBase + st * 32 + cA * 8 + 4);
        };
        auto loadB1 = [&](int st) {      // V'[k][a]: k=z*256..+256 rows
            #pragma unroll
            for (int p = 0; p < 8; ++p) {
                int n_off = w * 16 + p * 2 + (l >> 5);
                int q = (l >> 3) & 3, a_off = (l & 7) * 4;
                regB[p] = *(const float4*)&pool[(size_t)(z * 64 + n_off) * D_POOL + 1024 + q * 256 + st * 32 + a_off];
            }
        };
        auto writeA = [&](int buf) {
            int ch = cA ^ ((rA >> 1) & 3);
            ushort4 u0 = {bfb(regA[0].x), bfb(regA[0].y), bfb(regA[0].z), bfb(regA[0].w)};
            ushort4 u1 = {bfb(regA[1].x), bfb(regA[1].y), bfb(regA[1].z), bfb(regA[1].w)};
            *(ushort4*)&As[buf * 2048 + rA * 32 + (ch << 3)] = u0;
            *(ushort4*)&As[buf * 2048 + rA * 32 + (ch << 3) + 4] = u1;
        };
        auto writeB1 = [&](int buf) {
            #pragma unroll
            for (int p = 0; p < 8; ++p) {
                int n_off = w * 16 + p * 2 + (l >> 5);
                int q = (l >> 3) & 3;
                int krel = n_off * 4 + q;
                int chunk = (l & 7) >> 1, half = (l & 7) & 1;
                ushort4 u = {bfb(regB[p].x), bfb(regB[p].y), bfb(regB[p].z), bfb(regB[p].w)};
                *(ushort4*)&Bs[buf * 8192 + krel * 32 + ((chunk ^ ((krel >> 1) & 3)) << 3) + half * 4] = u;
            }
        };

        loadA1(0); loadB1(0); writeA(0); writeB1(0);
        __syncthreads();
        int cur = 0;
        #pragma unroll
        for (int it = 0; it < 7; ++it) {
            loadA1(it + 1); loadB1(it + 1);
            compute(cur);
            writeA(cur ^ 1); writeB1(cur ^ 1);
            __syncthreads();
            cur ^= 1;
        }
        compute(cur);

        // ---- s = alpha * acc -> S_ (swizzled bf16), then reset acc
        #pragma unroll
        for (int mi = 0; mi < 4; ++mi)
            #pragma unroll
            for (int ni = 0; ni < 4; ++ni) {
                int col = w * 64 + ni * 16 + l16;          // k_rel in z-slice
                #pragma unroll
                for (int e = 0; e < 4; ++e) {
                    int row = mi * 16 + l4 * 4 + e;
                    float av = alpha[(size_t)(b0 + row) * N_POOL + z * 64 + (col >> 2)];
                    int ch = (col >> 3) ^ (row & 7);
                    S_[row * 256 + (ch << 3) + (col & 7)] = bfb(acc[mi][ni][e] * av);
                }
                acc[mi][ni] = (f32x4){0.f, 0.f, 0.f, 0.f};
            }
        __syncthreads();

        // ================= phase 2: GEMM2 s @ U' (K=256 over k, 8 steps) =================
        auto loadB2 = [&](int st) {      // U'[k][c] = pool[k>>2][c*4+q]
            #pragma unroll
            for (int p = 0; p < 8; ++p) {
                int n_off = w * 2 + (p >> 2);
                int cblk = p & 3;
                regB[p] = *(const float4*)&pool[(size_t)(z * 64 + st * 8 + n_off) * D_POOL + (cblk * 64 + l) * 4];
            }
        };
        auto writeB2 = [&](int buf) {
            #pragma unroll
            for (int p = 0; p < 8; ++p) {
                int n_off = w * 2 + (p >> 2);
                int c = (p & 3) * 64 + l;
                int chunk = n_off >> 1, half = n_off & 1;
                ushort4 u = {bfb(regB[p].x), bfb(regB[p].y), bfb(regB[p].z), bfb(regB[p].w)};
                *(ushort4*)&Bs[buf * 8192 + c * 32 + ((chunk ^ ((c >> 1) & 3)) << 3) + half * 4] = u;
            }
        };
        auto compute2 = [&](int buf, int st) {
            bf16x8 af[4], bv[4];
            #pragma unroll
            for (int mi = 0; mi < 4; ++mi) {
                int ar = mi * 16 + l16;
                int ch = (st * 4 + l4) ^ (ar & 7);
                af[mi] = *(const bf16x8*)&S_[ar * 256 + (ch << 3)];
            }
            #pragma unroll
            for (int ni = 0; ni < 4; ++ni) {
                int br = w * 64 + ni * 16 + l16;
                bv[ni] = *(const bf16x8*)&Bs[buf * 8192 + br * 32 + ((l4 ^ ((br >> 1) & 3)) << 3)];
            }
            #pragma unroll
            for (int mi = 0; mi < 4; ++mi)
                #pragma unroll
                for (int ni = 0; ni < 4; ++ni)
                    acc[mi][ni] = __builtin_amdgcn_mfma_f32_16x16x32_bf16(af[mi], bv[ni], acc[mi][ni], 0, 0, 0);
        };

        loadB2(0); writeB2(0);
        __syncthreads();
        cur = 0;
        #pragma unroll
        for (int it = 0; it < 7; ++it) {
            loadB2(it + 1);
            compute2(cur, it);
            writeB2(cur ^ 1);
            __syncthreads();
            cur ^= 1;
        }
        compute2(cur, 7);

        // ---- epilogue: acc -> S_ (bf16, swizzled) -> coalesced plane-z write
        __syncthreads();                 // all waves done reading S_ (phase-2 A)
        #pragma unroll
        for (int mi = 0; mi < 4; ++mi)
            #pragma unroll
            for (int ni = 0; ni < 4; ++ni) {
                int col = w * 64 + ni * 16 + l16;
                #pragma unroll
                for (int e = 0; e < 4; ++e) {
                    int row = mi * 16 + l4 * 4 + e;
                    int ch = (col >> 3) ^ (row & 7);
                    S_[row * 256 + (ch << 3) + (col & 7)] = bfb(acc[mi][ni][e]);
                }
            }
        __syncthreads();
        {
            int row = t >> 2;
            ushort_t* P = part + (size_t)z * (2048 * 256) + (size_t)(b0 + row) * 256;
            #pragma unroll
            for (int p = 0; p < 8; ++p) {
                int ch = (t & 3) * 8 + p;
                bf16x8 v = *(const bf16x8*)&S_[row * 256 + ((ch ^ (row & 7)) << 3)];
                *(bf16x8*)&P[ch * 8] = v;
            }
        }
        return;
    }

    // ================= base paths (R17-verified bodies) =================
    ushort_t* As = shm;                  // [2][4096] : 64x64 tiles
    ushort_t* Bs = shm + 8192;
    const int wr = w >> 1, wc = w & 1;
    const int row = t >> 2, cs = t & 3;

    f32x4 acc[2][2];
    #pragma unroll
    for (int i = 0; i < 2; ++i)
        #pragma unroll
        for (int j = 0; j < 2; ++j) acc[i][j] = (f32x4){0.f, 0.f, 0.f, 0.f};

    float4 aR[4], bR[4];

    auto writeLDS_AB = [&](int buf) {
        #pragma unroll
        for (int p = 0; p < 4; ++p) {
            int c0 = (cs + p * 4) << 2;
            int off = row * 64 + (((c0 >> 3) ^ (row & 7)) << 3) + ((c0 >> 2) & 1) * 4;
            ushort4 ua = {bfb(aR[p].x), bfb(aR[p].y), bfb(aR[p].z), bfb(aR[p].w)};
            ushort4 ub = {bfb(bR[p].x), bfb(bR[p].y), bfb(bR[p].z), bfb(bR[p].w)};
            *(ushort4*)&As[buf * 4096 + off] = ua;
            *(ushort4*)&Bs[buf * 4096 + off] = ub;
        }
    };
    auto compute64 = [&](int buf) {
        bf16x8 af[2][2], bv[2][2];
        #pragma unroll
        for (int mi = 0; mi < 2; ++mi) {
            int arow = wr * 32 + mi * 16 + l16;
            #pragma unroll
            for (int ks = 0; ks < 2; ++ks)
                af[mi][ks] = *(const bf16x8*)&As[buf * 4096 + arow * 64 + (((ks * 4 + l4) ^ (arow & 7)) << 3)];
        }
        #pragma unroll
        for (int ni = 0; ni < 2; ++ni) {
            int brow = wc * 32 + ni * 16 + l16;
            #pragma unroll
            for (int ks = 0; ks < 2; ++ks)
                bv[ni][ks] = *(const bf16x8*)&Bs[buf * 4096 + brow * 64 + (((ks * 4 + l4) ^ (brow & 7)) << 3)];
        }
        #pragma unroll
        for (int ks = 0; ks < 2; ++ks)
            #pragma unroll
            for (int mi = 0; mi < 2; ++mi)
                #pragma unroll
                for (int ni = 0; ni < 2; ++ni)
                    acc[mi][ni] = __builtin_amdgcn_mfma_f32_16x16x32_bf16(af[mi][ks], bv[ni][ks], acc[mi][ni], 0, 0, 0);
    };
    auto epilogueLDS = [&]() {
        __syncthreads();
        float* sc = (float*)shm;
        #pragma unroll
        for (int mi = 0; mi < 2; ++mi)
            #pragma unroll
            for (int ni = 0; ni < 2; ++ni)
                #pragma unroll
                for (int e = 0; e < 4; ++e)
                    sc[(wr * 32 + mi * 16 + l4 * 4 + e) * 64 + wc * 32 + ni * 16 + l16] = acc[mi][ni][e];
        __syncthreads();
    };

    if (bid < 384) {  // ---------------- baseW: hA @ Wb^T (K=256) -> plane 8 ----------------
        const int b2 = bid - 256;
        const int bm0 = (b2 >> 2) * 64, bc0 = (b2 & 3) * 64;
        const float* abase = hA + (size_t)(bm0 + row) * 256;
        const float* bbase = Wb + (size_t)(bc0 + row) * 256;
        auto loadRegs = [&](int step) {
            const int a0 = step * 64;
            #pragma unroll
            for (int p = 0; p < 4; ++p) {
                int c0 = (cs + p * 4) << 2;
                aR[p] = *(const float4*)(abase + a0 + c0);
                bR[p] = *(const float4*)(bbase + a0 + c0);
            }
        };
        loadRegs(0); writeLDS_AB(0); __syncthreads();
        int cur = 0;
        #pragma unroll
        for (int it = 0; it < 3; ++it) {
            loadRegs(it + 1);
            compute64(cur);
            writeLDS_AB(cur ^ 1);
            __syncthreads();
            cur ^= 1;
        }
        compute64(cur);
        epilogueLDS();
        float* sc = (float*)shm;
        const int r2 = t >> 2, c0 = (t & 3) * 16;
        __align__(16) ushort_t u[16];
        #pragma unroll
        for (int j = 0; j < 16; ++j) u[j] = bfb(sc[r2 * 64 + c0 + j]);
        ushort_t* P = part + (size_t)8 * (2048 * 256) + (size_t)(bm0 + r2) * 256 + bc0 + c0;
        *(uint4*)P = ((uint4*)u)[0];
        *(uint4*)(P + 8) = ((uint4*)u)[1];
        return;
    }

    {  // ---------------- baseB: alpha @ bias^T (K=512) -> plane 9 ----------------
        const int b2 = bid - 384;
        const int bm0 = (b2 >> 2) * 64, bc0 = (b2 & 3) * 64;
        const float* abase = alpha + (size_t)(bm0 + row) * N_POOL;
        const int cg = t & 63;
        const int jg = t >> 6;
        float bRv[16];
        auto loadRegsB = [&](int step) {
            const int j0 = step * 64;
            #pragma unroll
            for (int p = 0; p < 4; ++p) {
                int c0 = (cs + p * 4) << 2;
                aR[p] = *(const float4*)(abase + j0 + c0);
            }
            #pragma unroll
            for (int p = 0; p < 16; ++p)
                bRv[p] = pool[(size_t)(j0 + jg * 16 + p) * D_POOL + 2048 + bc0 + cg];
        };
        auto writeLDSB = [&](int buf) {
            #pragma unroll
            for (int p = 0; p < 4; ++p) {
                int c0 = (cs + p * 4) << 2;
                int off = row * 64 + (((c0 >> 3) ^ (row & 7)) << 3) + ((c0 >> 2) & 1) * 4;
                ushort4 ua = {bfb(aR[p].x), bfb(aR[p].y), bfb(aR[p].z), bfb(aR[p].w)};
                *(ushort4*)&As[buf * 4096 + off] = ua;
            }
            #pragma unroll
            for (int p = 0; p < 16; ++p) {
                int jj = jg * 16 + p;
                Bs[buf * 4096 + cg * 64 + (((jj >> 3) ^ (cg & 7)) << 3) + (jj & 7)] = bfb(bRv[p]);
            }
        };
        loadRegsB(0); writeLDSB(0); __syncthreads();
        int cur = 0;
        #pragma unroll
        for (int it = 0; it < 7; ++it) {   // K=512 -> 8 steps
            loadRegsB(it + 1);
            compute64(cur);
            writeLDSB(cur ^ 1);
            __syncthreads();
            cur ^= 1;
        }
        compute64(cur);
        epilogueLDS();
        float* sc = (float*)shm;
        const int r2 = t >> 2, c0 = (t & 3) * 16;
        __align__(16) ushort_t u[16];
        #pragma unroll
        for (int j = 0; j < 16; ++j) u[j] = bfb(sc[r2 * 64 + c0 + j]);
        ushort_t* P = part + (size_t)9 * (2048 * 256) + (size_t)(bm0 + r2) * 256 + bc0 + c0;
        *(uint4*)P = ((uint4*)u)[0];
        *(uint4*)(P + 8) = ((uint4*)u)[1];
    }
}

// ================= kC: sum 10 bf16 partials + b_base; residual; LN =================
__global__ __launch_bounds__(256) void kC(const ushort_t* __restrict__ part,
                                          const float* __restrict__ hA,
                                          const float* __restrict__ bb,
                                          const float* __restrict__ gamma_p,
                                          const float* __restrict__ lns,
                                          const float* __restrict__ lnb,
                                          float* __restrict__ out) {
    const int wave = threadIdx.x >> 6;
    const int lane = threadIdx.x & 63;
    const int b = blockIdx.x * 4 + wave;
    const float g = gamma_p[0];
    const size_t base = (size_t)b * 256 + lane * 4;

    float p0 = 0.f, p1 = 0.f, p2 = 0.f, p3 = 0.f;
    #pragma unroll
    for (int z = 0; z < 10; ++z) {
        ushort4 q = *(const ushort4*)&part[(size_t)z * 2048 * 256 + base];
        p0 += bf2f(q.x); p1 += bf2f(q.y); p2 += bf2f(q.z); p3 += bf2f(q.w);
    }
    float4 h  = *(const float4*)&hA[base];
    float4 b4 = *(const float4*)&bb[lane * 4];
    float y0 = h.x + g * (p0 + b4.x);
    float y1 = h.y + g * (p1 + b4.y);
    float y2 = h.z + g * (p2 + b4.z);
    float y3 = h.w + g * (p3 + b4.w);

    float sum = y0 + y1 + y2 + y3;
    float ss  = y0*y0 + y1*y1 + y2*y2 + y3*y3;
    #pragma unroll
    for (int off = 1; off < 64; off <<= 1) {
        sum += __shfl_xor(sum, off);
        ss  += __shfl_xor(ss, off);
    }
    float mu  = sum * (1.0f / 256.0f);
    float var = ss * (1.0f / 256.0f) - mu * mu;
    float inv = rsqrtf(var + 1e-5f);

    float4 sc = *(const float4*)&lns[lane * 4];
    float4 bi = *(const float4*)&lnb[lane * 4];
    float4 o;
    o.x = (y0 - mu) * inv * sc.x + bi.x;
    o.y = (y1 - mu) * inv * sc.y + bi.y;
    o.z = (y2 - mu) * inv * sc.z + bi.z;
    o.w = (y3 - mu) * inv * sc.w + bi.w;
    *(float4*)&out[base] = o;
}

extern "C" void kernel_launch(void* const* d_in, const int* in_sizes, int n_in,
                              void* d_out, int out_size, void* d_ws, size_t ws_size,
                              hipStream_t stream) {
    const float* hA    = (const float*)d_in[0];
    const float* pool  = (const float*)d_in[1];
    const float* alpha = (const float*)d_in[2];
    const float* Wb    = (const float*)d_in[3];
    const float* bb    = (const float*)d_in[4];
    const float* gamma = (const float*)d_in[5];
    const float* lns   = (const float*)d_in[6];
    const float* lnb   = (const float*)d_in[7];
    float* out = (float*)d_out;

    ushort_t* part = (ushort_t*)d_ws;                  // [10][2048][256] bf16

    kFused<<<512, 256, 0, stream>>>(hA, pool, alpha, Wb, part);
    kC<<<512, 256, 0, stream>>>(part, hA, bb, gamma, lns, lnb, out);
}

// Round 19
// 30.404 us; speedup vs baseline: 1.1641x; 1.0414x over previous
//
#include <hip/hip_runtime.h>
#include <hip/hip_bf16.h>

// R19 = EXACT R12 restore (session best: 30.36us). Terminal configuration.
//   kFront (3168): GEMM1 reg-staged (blocks 0..1023) + all prep packed.
//   kB (1024): GEMM2 64x64 splitK x8 uneven, XCD z-locality mapping, bf16 partials.
//   kC (512): sum 8 partials + b_base, residual, LayerNorm.
// FINAL LEDGER (all measured): F~9.6 fixed/replay + kFront~6 (L2-BW floor)
//   + kB~12 (7.3 warm L2-BW floor + ~5 cold first-touch, survived 6 attacks)
//   + kC~3 (HBM floor) = 30.6 ~= measured 30.36.
// Graveyard: per-block threadfence (-100us), coop-launch (capacity), 128^2 kB
// tile (occupancy), nt stores (+2), counted-vmcnt (0), K-consolidation (+5),
// full fusion (+1.3). R12 is the floor of this decomposition on this harness.

typedef __attribute__((ext_vector_type(8))) short bf16x8;
typedef __attribute__((ext_vector_type(4))) float f32x4;
typedef unsigned short ushort_t;

#define LDA_X 2816
#define N_POOL 512
#define D_POOL 4096

__device__ __forceinline__ void gld16(const ushort_t* g, ushort_t* l) {
    __builtin_amdgcn_global_load_lds((__attribute__((address_space(1))) void*)g,
                                     (__attribute__((address_space(3))) void*)l, 16, 0, 0);
}

__device__ __forceinline__ ushort_t bfb(float x) {
    union { __hip_bfloat16 h; ushort_t u; } c; c.h = __float2bfloat16(x); return c.u;
}

__device__ __forceinline__ float bf2f(ushort_t u) {
    union { unsigned int i; float f; } c; c.i = ((unsigned int)u) << 16; return c.f;
}

__device__ __forceinline__ void write4(ushort_t* p, float4 v) {
    ushort4 w = {bfb(v.x), bfb(v.y), bfb(v.z), bfb(v.w)};
    *(ushort4*)p = w;
}

// ================= kFront: GEMM1 (0..1023) + prep (1024..3167) =================
__global__ __launch_bounds__(256) void kFront(const float* __restrict__ hA,
                                              const float* __restrict__ pool,
                                              const float* __restrict__ alpha,
                                              const float* __restrict__ Wb,
                                              ushort_t* __restrict__ Xu,
                                              ushort_t* __restrict__ Mt) {
    __shared__ __align__(16) ushort_t shmem[16384];   // 32KB pool
    ushort_t* As = shmem;                             // [2][4096]
    ushort_t* Bs = shmem + 8192;
    const int t = threadIdx.x;
    const int bid = blockIdx.x;

    if (bid >= 1024) {  // ---------------- prep path ----------------
        const int b2 = bid - 1024;
        if (b2 < 512) {                    // X hA seg [2048][256]
            int idx = b2 * 256 + t, b = idx >> 6, a4 = (idx & 63) << 2;
            write4(Xu + (size_t)b * LDA_X + 2048 + a4, *(const float4*)&hA[(size_t)b * 256 + a4]);
        } else if (b2 < 1536) {            // X alpha seg [2048][512]
            int idx = (b2 - 512) * 256 + t, b = idx >> 7, j4 = (idx & 127) << 2;
            write4(Xu + (size_t)b * LDA_X + 2304 + j4, *(const float4*)&alpha[(size_t)b * 512 + j4]);
        } else if (b2 < 2048) {            // Mt U: [c][4n..] = pool[n][4c..]
            int idx = (b2 - 1536) * 256 + t, c = idx >> 9, n = idx & 511;
            write4(Mt + (size_t)c * LDA_X + (n << 2), *(const float4*)&pool[(size_t)n * D_POOL + (c << 2)]);
        } else if (b2 < 2112) {            // Mt Wb: [c][2048+q]
            int idx = (b2 - 2048) * 256 + t, c = idx >> 6, q = (idx & 63) << 2;
            write4(Mt + (size_t)c * LDA_X + 2048 + q, *(const float4*)&Wb[(size_t)c * 256 + q]);
        } else {                           // Mt bias via 64x64 LDS transpose
            float* Lf = (float*)shmem;     // [64][65] f32 = 16.6KB
            int tb = b2 - 2112;            // 0..31
            int j0 = (tb >> 2) * 64, c0t = (tb & 3) * 64;
            #pragma unroll
            for (int i = 0; i < 16; ++i) {
                int idx = i * 256 + t, jj = idx >> 6, cc = idx & 63;
                Lf[jj * 65 + cc] = pool[(size_t)(j0 + jj) * D_POOL + 2048 + c0t + cc];
            }
            __syncthreads();
            int cc = t >> 2, js = (t & 3) * 16;
            __align__(16) ushort_t u[16];
            #pragma unroll
            for (int j = 0; j < 16; ++j) u[j] = bfb(Lf[(js + j) * 65 + cc]);
            ushort_t* dst = Mt + (size_t)(c0t + cc) * LDA_X + 2304 + j0 + js;
            *(uint4*)dst = ((uint4*)u)[0];
            *(uint4*)(dst + 8) = ((uint4*)u)[1];
        }
        return;
    }

    // ---------------- GEMM1 path (reg-staged, verified) ----------------
    const int w = t >> 6, l = t & 63, l16 = l & 15, l4 = l >> 4;
    const int wr = w >> 1, wc = w & 1;
    const int bm0 = (bid >> 5) * 64, bn0 = (bid & 31) * 64;
    const int row = t >> 2, cs = t & 3;

    f32x4 acc[2][2];
    #pragma unroll
    for (int i = 0; i < 2; ++i)
        #pragma unroll
        for (int j = 0; j < 2; ++j) acc[i][j] = (f32x4){0.f, 0.f, 0.f, 0.f};

    float4 aR[4], bR[4];
    const int kk = bn0 + row;
    const float* bbase = pool + (size_t)(kk >> 2) * D_POOL + 1024 + (kk & 3) * 256;
    const float* abase = hA + (size_t)(bm0 + row) * 256;

    auto loadRegs = [&](int step) {
        const int a0 = step * 64;
        #pragma unroll
        for (int p = 0; p < 4; ++p) {
            int c0 = (cs + p * 4) << 2;
            aR[p] = *(const float4*)(abase + a0 + c0);
            bR[p] = *(const float4*)(bbase + a0 + c0);
        }
    };
    auto writeLDS = [&](int buf) {
        #pragma unroll
        for (int p = 0; p < 4; ++p) {
            int c0 = (cs + p * 4) << 2;
            int off = row * 64 + (((c0 >> 3) ^ (row & 7)) << 3) + ((c0 >> 2) & 1) * 4;
            ushort4 ua = {bfb(aR[p].x), bfb(aR[p].y), bfb(aR[p].z), bfb(aR[p].w)};
            ushort4 ub = {bfb(bR[p].x), bfb(bR[p].y), bfb(bR[p].z), bfb(bR[p].w)};
            *(ushort4*)&As[buf * 4096 + off] = ua;
            *(ushort4*)&Bs[buf * 4096 + off] = ub;
        }
    };
    auto compute = [&](int buf) {
        bf16x8 af[2][2], bv[2][2];
        #pragma unroll
        for (int mi = 0; mi < 2; ++mi) {
            int arow = wr * 32 + mi * 16 + l16;
            #pragma unroll
            for (int ks = 0; ks < 2; ++ks)
                af[mi][ks] = *(const bf16x8*)&As[buf * 4096 + arow * 64 + (((ks * 4 + l4) ^ (arow & 7)) << 3)];
        }
        #pragma unroll
        for (int ni = 0; ni < 2; ++ni) {
            int brow = wc * 32 + ni * 16 + l16;
            #pragma unroll
            for (int ks = 0; ks < 2; ++ks)
                bv[ni][ks] = *(const bf16x8*)&Bs[buf * 4096 + brow * 64 + (((ks * 4 + l4) ^ (brow & 7)) << 3)];
        }
        #pragma unroll
        for (int ks = 0; ks < 2; ++ks)
            #pragma unroll
            for (int mi = 0; mi < 2; ++mi)
                #pragma unroll
                for (int ni = 0; ni < 2; ++ni)
                    acc[mi][ni] = __builtin_amdgcn_mfma_f32_16x16x32_bf16(af[mi][ks], bv[ni][ks], acc[mi][ni], 0, 0, 0);
    };

    loadRegs(0);
    writeLDS(0);
    __syncthreads();
    int cur = 0;
    #pragma unroll
    for (int it = 0; it < 3; ++it) {       // K=256 -> 4 steps
        loadRegs(it + 1);
        compute(cur);
        writeLDS(cur ^ 1);
        __syncthreads();
        cur ^= 1;
    }
    compute(cur);

    __syncthreads();
    float* sc = (float*)shmem;             // 64x64 f32 = 16KB
    #pragma unroll
    for (int mi = 0; mi < 2; ++mi)
        #pragma unroll
        for (int ni = 0; ni < 2; ++ni)
            #pragma unroll
            for (int e = 0; e < 4; ++e)
                sc[(wr * 32 + mi * 16 + l4 * 4 + e) * 64 + wc * 32 + ni * 16 + l16] = acc[mi][ni][e];
    __syncthreads();
    const int r2 = t >> 2, c0 = (t & 3) * 16;
    const float* arow = alpha + (size_t)(bm0 + r2) * N_POOL;
    __align__(16) ushort_t u[16];
    #pragma unroll
    for (int j = 0; j < 16; ++j)
        u[j] = bfb(sc[r2 * 64 + c0 + j] * arow[(bn0 + c0 + j) >> 2]);
    ushort_t* dst = Xu + (size_t)(bm0 + r2) * LDA_X + bn0 + c0;
    *(uint4*)dst = ((uint4*)u)[0];
    *(uint4*)(dst + 8) = ((uint4*)u)[1];
}

// ================= kB: GEMM2 64x64, splitK x8, XCD z-locality mapping =================
__global__ __launch_bounds__(256) void kB(const ushort_t* __restrict__ Xu,
                                          const ushort_t* __restrict__ Mt,
                                          ushort_t* __restrict__ part) {
    __shared__ __align__(16) ushort_t As[2][4096];
    __shared__ __align__(16) ushort_t Bs[2][4096];
    const int t = threadIdx.x;
    const int w = t >> 6, l = t & 63, l16 = l & 15, l4 = l >> 4;
    const int wr = w >> 1, wc = w & 1;
    const int bid = blockIdx.x;                // 0..1023
    const int z = bid & 7;
    const int n = (bid >> 3) & 3;
    const int m = bid >> 5;
    const int bm0 = m * 64, bn0 = n * 64;
    const int steps = (z < 4) ? 6 : 5;
    const int kc0 = (z < 4) ? z * 384 : 1536 + (z - 4) * 320;
    const int srow = t >> 3;
    const int schunk = (t & 7) ^ (srow & 7);   // source-side swizzle (rule #21)

    f32x4 acc[2][2];
    #pragma unroll
    for (int i = 0; i < 2; ++i)
        #pragma unroll
        for (int j = 0; j < 2; ++j) acc[i][j] = (f32x4){0.f, 0.f, 0.f, 0.f};

    auto stage = [&](int buf, int k0) {
        #pragma unroll
        for (int h = 0; h < 2; ++h) {
            gld16(Xu + (size_t)(bm0 + srow + h * 32) * LDA_X + k0 + schunk * 8,
                  &As[buf][h * 2048 + w * 512]);
            gld16(Mt + (size_t)(bn0 + srow + h * 32) * LDA_X + k0 + schunk * 8,
                  &Bs[buf][h * 2048 + w * 512]);
        }
    };
    auto compute = [&](int buf) {
        bf16x8 af[2][2], bv[2][2];
        #pragma unroll
        for (int mi = 0; mi < 2; ++mi) {
            int arow = wr * 32 + mi * 16 + l16;
            #pragma unroll
            for (int ks = 0; ks < 2; ++ks)
                af[mi][ks] = *(const bf16x8*)&As[buf][arow * 64 + (((ks * 4 + l4) ^ (arow & 7)) << 3)];
        }
        #pragma unroll
        for (int ni = 0; ni < 2; ++ni) {
            int brow = wc * 32 + ni * 16 + l16;
            #pragma unroll
            for (int ks = 0; ks < 2; ++ks)
                bv[ni][ks] = *(const bf16x8*)&Bs[buf][brow * 64 + (((ks * 4 + l4) ^ (brow & 7)) << 3)];
        }
        #pragma unroll
        for (int ks = 0; ks < 2; ++ks)
            #pragma unroll
            for (int mi = 0; mi < 2; ++mi)
                #pragma unroll
                for (int ni = 0; ni < 2; ++ni)
                    acc[mi][ni] = __builtin_amdgcn_mfma_f32_16x16x32_bf16(af[mi][ks], bv[ni][ks], acc[mi][ni], 0, 0, 0);
    };

    stage(0, kc0);
    __syncthreads();
    int cur = 0;
    for (int it = 0; it < steps - 1; ++it) {
        stage(cur ^ 1, kc0 + (it + 1) * 64);
        compute(cur);
        __syncthreads();
        cur ^= 1;
    }
    compute(cur);

    // epilogue: acc -> LDS f32 -> bf16, 2x16B stores/thread
    __syncthreads();
    float* sc = (float*)&As[0][0];
    #pragma unroll
    for (int mi = 0; mi < 2; ++mi)
        #pragma unroll
        for (int ni = 0; ni < 2; ++ni)
            #pragma unroll
            for (int e = 0; e < 4; ++e)
                sc[(wr * 32 + mi * 16 + l4 * 4 + e) * 64 + wc * 32 + ni * 16 + l16] = acc[mi][ni][e];
    __syncthreads();
    const int r2 = t >> 2, c0 = (t & 3) * 16;
    __align__(16) ushort_t u[16];
    #pragma unroll
    for (int j = 0; j < 16; ++j) u[j] = bfb(sc[r2 * 64 + c0 + j]);
    ushort_t* P = part + (size_t)z * (2048 * 256) + (size_t)(bm0 + r2) * 256 + bn0 + c0;
    *(uint4*)P = ((uint4*)u)[0];
    *(uint4*)(P + 8) = ((uint4*)u)[1];
}

// ================= kC: sum 8 bf16 partials + b_base; residual; LN =================
__global__ __launch_bounds__(256) void kC(const ushort_t* __restrict__ part,
                                          const float* __restrict__ hA,
                                          const float* __restrict__ bb,
                                          const float* __restrict__ gamma_p,
                                          const float* __restrict__ lns,
                                          const float* __restrict__ lnb,
                                          float* __restrict__ out) {
    const int wave = threadIdx.x >> 6;
    const int lane = threadIdx.x & 63;
    const int b = blockIdx.x * 4 + wave;
    const float g = gamma_p[0];
    const size_t base = (size_t)b * 256 + lane * 4;

    float p0 = 0.f, p1 = 0.f, p2 = 0.f, p3 = 0.f;
    #pragma unroll
    for (int z = 0; z < 8; ++z) {
        ushort4 q = *(const ushort4*)&part[(size_t)z * 2048 * 256 + base];
        p0 += bf2f(q.x); p1 += bf2f(q.y); p2 += bf2f(q.z); p3 += bf2f(q.w);
    }
    float4 h  = *(const float4*)&hA[base];
    float4 b4 = *(const float4*)&bb[lane * 4];
    float y0 = h.x + g * (p0 + b4.x);
    float y1 = h.y + g * (p1 + b4.y);
    float y2 = h.z + g * (p2 + b4.z);
    float y3 = h.w + g * (p3 + b4.w);

    float sum = y0 + y1 + y2 + y3;
    float ss  = y0*y0 + y1*y1 + y2*y2 + y3*y3;
    #pragma unroll
    for (int off = 1; off < 64; off <<= 1) {
        sum += __shfl_xor(sum, off);
        ss  += __shfl_xor(ss, off);
    }
    float mu  = sum * (1.0f / 256.0f);
    float var = ss * (1.0f / 256.0f) - mu * mu;
    float inv = rsqrtf(var + 1e-5f);

    float4 sc = *(const float4*)&lns[lane * 4];
    float4 bi = *(const float4*)&lnb[lane * 4];
    float4 o;
    o.x = (y0 - mu) * inv * sc.x + bi.x;
    o.y = (y1 - mu) * inv * sc.y + bi.y;
    o.z = (y2 - mu) * inv * sc.z + bi.z;
    o.w = (y3 - mu) * inv * sc.w + bi.w;
    *(float4*)&out[base] = o;
}

extern "C" void kernel_launch(void* const* d_in, const int* in_sizes, int n_in,
                              void* d_out, int out_size, void* d_ws, size_t ws_size,
                              hipStream_t stream) {
    const float* hA    = (const float*)d_in[0];
    const float* pool  = (const float*)d_in[1];
    const float* alpha = (const float*)d_in[2];
    const float* Wb    = (const float*)d_in[3];
    const float* bb    = (const float*)d_in[4];
    const float* gamma = (const float*)d_in[5];
    const float* lns   = (const float*)d_in[6];
    const float* lnb   = (const float*)d_in[7];
    float* out = (float*)d_out;

    ushort_t* Xu   = (ushort_t*)d_ws;                  // [2048][2816] bf16
    ushort_t* Mt   = Xu + (size_t)2048 * LDA_X;        // [256][2816]  bf16
    ushort_t* part = Mt + (size_t)256 * LDA_X;         // [8][2048][256] bf16

    kFront<<<3168, 256, 0, stream>>>(hA, pool, alpha, Wb, Xu, Mt);
    kB<<<1024, 256, 0, stream>>>(Xu, Mt, part);
    kC<<<512, 256, 0, stream>>>(part, hA, bb, gamma, lns, lnb, out);
}